// Round 1
// baseline (1454.242 us; speedup 1.0000x reference)
//
#include <hip/hip_runtime.h>

// WindowAttention: B=32, N=3136 (56x56), C=192, heads=6, d=32, ws=7, NW=49
// Plan:
//   k1: one block per (window, head-half): LN -> LDS, QKV gemm -> LDS(bf16),
//       per-(head,token) attention w/ 2-pass softmax, write pre-proj `out`
//       (spatial token order, bf16) to d_ws.
//   k2: dense proj GEMM (100352 x 192) @ (192 x 192)^T + bias -> d_out (fp32).

#define NTOK 100352   // 32*3136
#define CDIM 192

__device__ __forceinline__ float bflo(unsigned int u){
  union{unsigned int i; float f;} x; x.i = u << 16; return x.f;
}
__device__ __forceinline__ float bfhi(unsigned int u){
  union{unsigned int i; float f;} x; x.i = u & 0xffff0000u; return x.f;
}
__device__ __forceinline__ unsigned short f2bf(float f){
  union{float f; unsigned int i;} x; x.f = f;
  unsigned int r = x.i + 0x7fffu + ((x.i >> 16) & 1u);  // RNE
  return (unsigned short)(r >> 16);
}
// read 32 contiguous bf16 from LDS as 4x b128, expand to fp32
__device__ __forceinline__ void lds_bf32(const unsigned short* p, float* dst){
  const uint4* q4 = (const uint4*)p;
#pragma unroll
  for (int v = 0; v < 4; v++){
    uint4 a = q4[v];
    dst[v*8+0] = bflo(a.x); dst[v*8+1] = bfhi(a.x);
    dst[v*8+2] = bflo(a.y); dst[v*8+3] = bfhi(a.y);
    dst[v*8+4] = bflo(a.z); dst[v*8+5] = bfhi(a.z);
    dst[v*8+6] = bflo(a.w); dst[v*8+7] = bfhi(a.w);
  }
}

// ---------------- kernel 1: LN + QKV + windowed attention ----------------
// grid 4096 (2 blocks per window; each handles 3 heads), block 384 (6 waves)
__global__ __launch_bounds__(384, 1) void win_attn_k1(
    const float* __restrict__ x, const float* __restrict__ gamma,
    const float* __restrict__ rpb, const float* __restrict__ qkv_w,
    const float* __restrict__ qkv_b, unsigned short* __restrict__ wsout)
{
  __shared__ __align__(16) unsigned short xn[49*192];  // LN output, bf16
  __shared__ __align__(16) unsigned short qs[49*96];   // q (scaled), 3 heads
  __shared__ __align__(16) unsigned short ks[49*96];
  __shared__ __align__(16) unsigned short vs[49*96];
  __shared__ float bias_s[169*6];

  const int blk = blockIdx.x;
  const int wi  = blk >> 1;        // window 0..2047
  const int h0  = (blk & 1) * 3;   // first head of this block
  const int b   = wi >> 6;
  const int wr  = (wi >> 3) & 7;
  const int wc  = wi & 7;
  const int tid = threadIdx.x;

  for (int i = tid; i < 169*6; i += 384) bias_s[i] = rpb[i];

  // ---- Phase 1: LayerNorm (one wave per token; lane covers 3 channels) ----
  {
    const int wave = tid >> 6, lane = tid & 63;
    const float* xb = x + (size_t)b * 3136 * CDIM;
    for (int t = wave; t < 49; t += 6){
      int r = t / 7, c = t - r*7;
      const float* xt = xb + (size_t)((wr*7 + r)*56 + (wc*7 + c)) * CDIM;
      float v0 = xt[lane], v1 = xt[lane+64], v2 = xt[lane+128];
      float s  = v0 + v1 + v2;
      float sq = v0*v0 + v1*v1 + v2*v2;
#pragma unroll
      for (int off = 32; off > 0; off >>= 1){
        s  += __shfl_xor(s,  off);
        sq += __shfl_xor(sq, off);
      }
      float mu  = s * (1.0f/192.0f);
      float var = sq * (1.0f/192.0f) - mu*mu;
      float inv = rsqrtf(var + 1e-5f);
      xn[t*192 + lane      ] = f2bf((v0 - mu)*inv*gamma[lane      ]);
      xn[t*192 + lane + 64 ] = f2bf((v1 - mu)*inv*gamma[lane + 64 ]);
      xn[t*192 + lane + 128] = f2bf((v2 - mu)*inv*gamma[lane + 128]);
    }
  }
  __syncthreads();

  // ---- Phase 2: QKV projection for this block's 96 channels ----
  // thread = (ug: channel 0..95) x (tg: token group 0..3, 13 tokens each)
  {
    const int ug = tid % 96;
    const int tg = tid / 96;
    const int t0 = tg * 13;
    const int uq = 0*192 + h0*32 + ug;
    const int uk = 1*192 + h0*32 + ug;
    const int uv = 2*192 + h0*32 + ug;
    const float* wq = qkv_w + (size_t)uq * CDIM;
    const float* wk = qkv_w + (size_t)uk * CDIM;
    const float* wv = qkv_w + (size_t)uv * CDIM;

    float acc[3][13];
#pragma unroll
    for (int j = 0; j < 3; j++)
#pragma unroll
      for (int i = 0; i < 13; i++) acc[j][i] = 0.f;

    for (int c = 0; c < CDIM; c += 8){
      float wreg[3][8];
      {
        const float4* p;
        float4 a0, a1;
        p = (const float4*)(wq + c); a0 = p[0]; a1 = p[1];
        wreg[0][0]=a0.x; wreg[0][1]=a0.y; wreg[0][2]=a0.z; wreg[0][3]=a0.w;
        wreg[0][4]=a1.x; wreg[0][5]=a1.y; wreg[0][6]=a1.z; wreg[0][7]=a1.w;
        p = (const float4*)(wk + c); a0 = p[0]; a1 = p[1];
        wreg[1][0]=a0.x; wreg[1][1]=a0.y; wreg[1][2]=a0.z; wreg[1][3]=a0.w;
        wreg[1][4]=a1.x; wreg[1][5]=a1.y; wreg[1][6]=a1.z; wreg[1][7]=a1.w;
        p = (const float4*)(wv + c); a0 = p[0]; a1 = p[1];
        wreg[2][0]=a0.x; wreg[2][1]=a0.y; wreg[2][2]=a0.z; wreg[2][3]=a0.w;
        wreg[2][4]=a1.x; wreg[2][5]=a1.y; wreg[2][6]=a1.z; wreg[2][7]=a1.w;
      }
#pragma unroll
      for (int i = 0; i < 13; i++){
        int t = t0 + i; t = (t > 48) ? 48 : t;   // clamp (dup work, guarded store)
        uint4 u = *(const uint4*)(&xn[t*192 + c]);
        float xv[8];
        xv[0]=bflo(u.x); xv[1]=bfhi(u.x);
        xv[2]=bflo(u.y); xv[3]=bfhi(u.y);
        xv[4]=bflo(u.z); xv[5]=bfhi(u.z);
        xv[6]=bflo(u.w); xv[7]=bfhi(u.w);
#pragma unroll
        for (int e = 0; e < 8; e++){
          acc[0][i] += xv[e]*wreg[0][e];
          acc[1][i] += xv[e]*wreg[1][e];
          acc[2][i] += xv[e]*wreg[2][e];
        }
      }
    }
    const float scale = 0.17677669529663687f;  // 1/sqrt(32)
    const float bq = qkv_b[uq], bk = qkv_b[uk], bv = qkv_b[uv];
#pragma unroll
    for (int i = 0; i < 13; i++){
      int t = t0 + i;
      if (t < 49){
        qs[t*96 + ug] = f2bf((acc[0][i] + bq) * scale);
        ks[t*96 + ug] = f2bf(acc[1][i] + bk);
        vs[t*96 + ug] = f2bf(acc[2][i] + bv);
      }
    }
  }
  __syncthreads();

  // ---- Phase 3: attention, one thread per (local head, query token) ----
  if (tid < 3*49){
    const int hl = tid / 49;
    const int t  = tid - hl*49;
    const int head = h0 + hl;
    const int tr = t / 7, tc = t - tr*7;

    float q[32];
    lds_bf32(&qs[t*96 + hl*32], q);

    float m = -1e30f;
    for (int j = 0; j < 49; j++){
      float kv[32];
      lds_bf32(&ks[j*96 + hl*32], kv);
      float s = 0.f;
#pragma unroll
      for (int dd = 0; dd < 32; dd++) s += q[dd]*kv[dd];
      int jr = j / 7, jc = j - jr*7;
      s += bias_s[((tr - jr + 6)*13 + (tc - jc + 6))*6 + head];
      m = fmaxf(m, s);
    }
    float o[32];
#pragma unroll
    for (int dd = 0; dd < 32; dd++) o[dd] = 0.f;
    float l = 0.f;
    for (int j = 0; j < 49; j++){
      float kv[32];
      lds_bf32(&ks[j*96 + hl*32], kv);
      float s = 0.f;
#pragma unroll
      for (int dd = 0; dd < 32; dd++) s += q[dd]*kv[dd];
      int jr = j / 7, jc = j - jr*7;
      s += bias_s[((tr - jr + 6)*13 + (tc - jc + 6))*6 + head];
      float p = __expf(s - m);
      l += p;
      float vv[32];
      lds_bf32(&vs[j*96 + hl*32], vv);
#pragma unroll
      for (int dd = 0; dd < 32; dd++) o[dd] += p*vv[dd];
    }
    const float inv = 1.f / l;
    // write pre-proj out in FINAL spatial order (window-reverse applied here)
    const size_t base =
        ((size_t)(b*3136) + (size_t)((wr*7 + tr)*56 + (wc*7 + tc))) * CDIM + head*32;
    uint4* wp = (uint4*)(wsout + base);
#pragma unroll
    for (int v = 0; v < 4; v++){
      uint4 u;
      u.x = (unsigned)f2bf(o[v*8+0]*inv) | ((unsigned)f2bf(o[v*8+1]*inv) << 16);
      u.y = (unsigned)f2bf(o[v*8+2]*inv) | ((unsigned)f2bf(o[v*8+3]*inv) << 16);
      u.z = (unsigned)f2bf(o[v*8+4]*inv) | ((unsigned)f2bf(o[v*8+5]*inv) << 16);
      u.w = (unsigned)f2bf(o[v*8+6]*inv) | ((unsigned)f2bf(o[v*8+7]*inv) << 16);
      wp[v] = u;
    }
  }
}

// ---------------- kernel 2: output projection ----------------
// grid 1568 (64 tokens per block), block 256
__global__ __launch_bounds__(256, 1) void win_attn_k2(
    const unsigned short* __restrict__ a, const float* __restrict__ pw,
    const float* __restrict__ pb, float* __restrict__ out)
{
  __shared__ __align__(16) unsigned short at[64*192];
  const int g0  = blockIdx.x * 64;
  const int tid = threadIdx.x;

  // stage 64x192 bf16 tile (coalesced b128)
  {
    const uint4* src = (const uint4*)(a + (size_t)g0 * CDIM);
    uint4* dst = (uint4*)at;
    for (int i = tid; i < 64*192/8; i += 256) dst[i] = src[i];
  }
  __syncthreads();

  const int ug = tid & 63;   // output cols: ug, ug+64, ug+128
  const int tg = tid >> 6;   // token group, 16 tokens
  const int t0 = tg * 16;
  const float* w0 = pw + (size_t)(ug      ) * CDIM;
  const float* w1 = pw + (size_t)(ug + 64 ) * CDIM;
  const float* w2 = pw + (size_t)(ug + 128) * CDIM;

  float acc[3][16];
#pragma unroll
  for (int j = 0; j < 3; j++)
#pragma unroll
    for (int i = 0; i < 16; i++) acc[j][i] = 0.f;

  for (int c = 0; c < CDIM; c += 8){
    float wreg[3][8];
    {
      const float4* p;
      float4 a0, a1;
      p = (const float4*)(w0 + c); a0 = p[0]; a1 = p[1];
      wreg[0][0]=a0.x; wreg[0][1]=a0.y; wreg[0][2]=a0.z; wreg[0][3]=a0.w;
      wreg[0][4]=a1.x; wreg[0][5]=a1.y; wreg[0][6]=a1.z; wreg[0][7]=a1.w;
      p = (const float4*)(w1 + c); a0 = p[0]; a1 = p[1];
      wreg[1][0]=a0.x; wreg[1][1]=a0.y; wreg[1][2]=a0.z; wreg[1][3]=a0.w;
      wreg[1][4]=a1.x; wreg[1][5]=a1.y; wreg[1][6]=a1.z; wreg[1][7]=a1.w;
      p = (const float4*)(w2 + c); a0 = p[0]; a1 = p[1];
      wreg[2][0]=a0.x; wreg[2][1]=a0.y; wreg[2][2]=a0.z; wreg[2][3]=a0.w;
      wreg[2][4]=a1.x; wreg[2][5]=a1.y; wreg[2][6]=a1.z; wreg[2][7]=a1.w;
    }
#pragma unroll
    for (int i = 0; i < 16; i++){
      uint4 u = *(const uint4*)(&at[(t0 + i)*192 + c]);
      float xv[8];
      xv[0]=bflo(u.x); xv[1]=bfhi(u.x);
      xv[2]=bflo(u.y); xv[3]=bfhi(u.y);
      xv[4]=bflo(u.z); xv[5]=bfhi(u.z);
      xv[6]=bflo(u.w); xv[7]=bfhi(u.w);
#pragma unroll
      for (int e = 0; e < 8; e++){
        acc[0][i] += xv[e]*wreg[0][e];
        acc[1][i] += xv[e]*wreg[1][e];
        acc[2][i] += xv[e]*wreg[2][e];
      }
    }
  }
  const float b0 = pb[ug], b1 = pb[ug+64], b2 = pb[ug+128];
#pragma unroll
  for (int i = 0; i < 16; i++){
    float* op = out + (size_t)(g0 + t0 + i) * CDIM;
    op[ug      ] = acc[0][i] + b0;
    op[ug + 64 ] = acc[1][i] + b1;
    op[ug + 128] = acc[2][i] + b2;
  }
}

extern "C" void kernel_launch(void* const* d_in, const int* in_sizes, int n_in,
                              void* d_out, int out_size, void* d_ws, size_t ws_size,
                              hipStream_t stream) {
  (void)in_sizes; (void)n_in; (void)out_size; (void)ws_size;
  const float* x      = (const float*)d_in[0];
  const float* gamma  = (const float*)d_in[1];
  const float* rpb    = (const float*)d_in[2];
  const float* qkv_w  = (const float*)d_in[3];
  const float* qkv_b  = (const float*)d_in[4];
  const float* proj_w = (const float*)d_in[5];
  const float* proj_b = (const float*)d_in[6];
  unsigned short* wsb = (unsigned short*)d_ws;   // 100352*192 bf16 = 38.5 MB
  float* out          = (float*)d_out;

  hipLaunchKernelGGL(win_attn_k1, dim3(4096), dim3(384), 0, stream,
                     x, gamma, rpb, qkv_w, qkv_b, wsb);
  hipLaunchKernelGGL(win_attn_k2, dim3(1568), dim3(256), 0, stream,
                     wsb, proj_w, proj_b, out);
}

// Round 3
// 455.946 us; speedup vs baseline: 3.1895x; 3.1895x over previous
//
#include <hip/hip_runtime.h>

// WindowAttention MFMA version: B=32, 56x56, C=192, heads=6, d=32, ws=7, NW=49
//  prep: fp32 weights -> bf16 in ws
//  k1:   per (window, 3-head half): LN -> MFMA QKV -> MFMA attention -> bf16 out (ws)
//  k2:   proj GEMM (100352x192x192) MFMA + bias -> fp32 d_out

typedef __bf16 bf16x8 __attribute__((ext_vector_type(8)));
typedef float  f32x4  __attribute__((ext_vector_type(4)));
union U128 { uint4 u; bf16x8 v; };

__device__ __forceinline__ f32x4 mfma16(bf16x8 a, bf16x8 b, f32x4 c){
  return __builtin_amdgcn_mfma_f32_16x16x32_bf16(a, b, c, 0, 0, 0);
}
__device__ __forceinline__ f32x4 f4zero(){
  f32x4 z; z[0]=0.f; z[1]=0.f; z[2]=0.f; z[3]=0.f; return z;
}

__device__ __forceinline__ float bf2f(unsigned short u){
  union{unsigned int i; float f;} x; x.i = ((unsigned int)u) << 16; return x.f;
}
__device__ __forceinline__ unsigned short f2bf(float f){
  union{float f; unsigned int i;} x; x.f = f;
  unsigned int r = x.i + 0x7fffu + ((x.i >> 16) & 1u);  // RNE
  return (unsigned short)(r >> 16);
}
__device__ __forceinline__ bf16x8 ldfrag(const unsigned short* p){
  U128 x; x.u = *(const uint4*)p; return x.v;
}
__device__ __forceinline__ int div7(int t){ return (t * 9363) >> 16; }  // exact for t<64

// ---------------- prep: weights fp32 -> bf16 ----------------
__global__ void wa_prep(const float* __restrict__ qkv_w, const float* __restrict__ proj_w,
                        unsigned short* __restrict__ wq, unsigned short* __restrict__ wp){
  int i = blockIdx.x * 256 + threadIdx.x;
  if (i < 576*192) wq[i] = f2bf(qkv_w[i]);
  if (i < 192*192) wp[i] = f2bf(proj_w[i]);
}

// ---------------- k1: LN + QKV + attention (MFMA) ----------------
// grid 4096 = 2048 windows x 2 half (3 heads each); block 384 (6 waves)
#define XNS 200   // padded xn row stride (bf16 elems), 16B-aligned rows, 2-way banks
__global__ __launch_bounds__(384, 3) void wa_k1(
    const float* __restrict__ x, const float* __restrict__ gamma,
    const float* __restrict__ rpb, const unsigned short* __restrict__ wq,
    const float* __restrict__ qkv_b, unsigned short* __restrict__ attn)
{
  __shared__ __align__(16) unsigned short uXP[64*XNS];   // xn, later P[3][64][64]
  __shared__ __align__(16) unsigned short qs[3*64*32];   // Q (scaled), row-major [hl][t][d]
  __shared__ __align__(16) unsigned short ks[3*64*32];   // K row-major
  __shared__ __align__(16) unsigned short vt[3*32*64];   // V transposed [hl][d][t]
  __shared__ unsigned short bias_s[169*6];

  const int blk  = blockIdx.x;
  const int wi   = blk >> 1;
  const int h0   = (blk & 1) * 3;
  const int b    = wi >> 6;
  const int wr   = (wi >> 3) & 7;
  const int wc   = wi & 7;
  const int tid  = threadIdx.x;
  const int wave = tid >> 6;
  const int lane = tid & 63;
  const int quad = lane >> 4;
  const int l16  = lane & 15;

  for (int i = tid; i < 169*6; i += 384) bias_s[i] = f2bf(rpb[i]);

  // ---- LayerNorm -> uXP (bf16, stride XNS), zero pad rows 49..63 ----
  {
    const float g0 = gamma[lane], g1 = gamma[lane+64], g2 = gamma[lane+128];
    const float* xb = x + (size_t)b * 3136 * 192;
    for (int t = wave; t < 49; t += 6){
      int r = div7(t), c = t - r*7;
      const float* xt = xb + (size_t)((wr*7 + r)*56 + (wc*7 + c)) * 192;
      float v0 = xt[lane], v1 = xt[lane+64], v2 = xt[lane+128];
      float s  = v0 + v1 + v2;
      float sq = v0*v0 + v1*v1 + v2*v2;
#pragma unroll
      for (int off = 32; off > 0; off >>= 1){
        s  += __shfl_xor(s,  off);
        sq += __shfl_xor(sq, off);
      }
      float mu  = s * (1.0f/192.0f);
      float var = sq * (1.0f/192.0f) - mu*mu;
      float inv = rsqrtf(var + 1e-5f);
      uXP[t*XNS + lane      ] = f2bf((v0 - mu)*inv*g0);
      uXP[t*XNS + lane + 64 ] = f2bf((v1 - mu)*inv*g1);
      uXP[t*XNS + lane + 128] = f2bf((v2 - mu)*inv*g2);
    }
    for (int i = tid; i < 15*XNS; i += 384) uXP[49*XNS + i] = 0;
  }
  __syncthreads();

  // ---- QKV GEMM: wave w computes 48 cols of [q|k|v] for its 3 heads ----
  // section = w>>1 (0:q 1:k 2:v); block-col bc in [ (w&1)*48, +48 )
  {
    const int sec = wave >> 1;
    const int n0  = sec*192 + h0*32 + (wave & 1)*48;   // global qkv_w row base
    f32x4 acc[4][3];
#pragma unroll
    for (int mt = 0; mt < 4; mt++)
#pragma unroll
      for (int nt = 0; nt < 3; nt++) acc[mt][nt] = f4zero();

#pragma unroll
    for (int kt = 0; kt < 6; kt++){
      bf16x8 a[4], bw[3];
#pragma unroll
      for (int mt = 0; mt < 4; mt++)
        a[mt] = ldfrag(&uXP[(mt*16 + l16)*XNS + kt*32 + quad*8]);
#pragma unroll
      for (int nt = 0; nt < 3; nt++)
        bw[nt] = ldfrag(&wq[(size_t)(n0 + nt*16 + l16)*192 + kt*32 + quad*8]);
#pragma unroll
      for (int mt = 0; mt < 4; mt++)
#pragma unroll
        for (int nt = 0; nt < 3; nt++)
          acc[mt][nt] = mfma16(a[mt], bw[nt], acc[mt][nt]);
    }
    const float scale = 0.17677669529663687f;  // 1/sqrt(32)
#pragma unroll
    for (int nt = 0; nt < 3; nt++){
      const int bc = (wave & 1)*48 + nt*16 + l16;  // 0..95 within section
      const int hl = bc >> 5, d = bc & 31;
      const float bias = qkv_b[n0 + nt*16 + l16];
#pragma unroll
      for (int mt = 0; mt < 4; mt++)
#pragma unroll
        for (int r = 0; r < 4; r++){
          const int row = mt*16 + quad*4 + r;
          const float val = acc[mt][nt][r] + bias;
          if (sec == 0)      qs[(hl*64 + row)*32 + d] = f2bf(val * scale);
          else if (sec == 1) ks[(hl*64 + row)*32 + d] = f2bf(val);
          else               vt[(hl*32 + d)*64 + row] = f2bf(val);
        }
    }
  }
  __syncthreads();

  // ---- Attention: wave -> (local head hl = w>>1, row-half = w&1) ----
  {
    const int hl   = wave >> 1;
    const int half = wave & 1;
    const int head = h0 + hl;

    bf16x8 aq[2];
#pragma unroll
    for (int i = 0; i < 2; i++)
      aq[i] = ldfrag(&qs[(hl*64 + half*32 + i*16 + l16)*32 + quad*8]);

    f32x4 s[2][4];
#pragma unroll
    for (int nt = 0; nt < 4; nt++){
      bf16x8 bk = ldfrag(&ks[(hl*64 + nt*16 + l16)*32 + quad*8]);
#pragma unroll
      for (int i = 0; i < 2; i++)
        s[i][nt] = mfma16(aq[i], bk, f4zero());
    }

    // bias + mask
    const int jj = l16;   // col low part
#pragma unroll
    for (int nt = 0; nt < 4; nt++){
      const int j = nt*16 + jj;
      const bool jok = (j < 49);
      const int jr = jok ? div7(j) : 0;
      const int jc = j - jr*7;
#pragma unroll
      for (int i = 0; i < 2; i++)
#pragma unroll
        for (int r = 0; r < 4; r++){
          int t  = half*32 + i*16 + quad*4 + r;
          int tc = (t > 48) ? 48 : t;
          int tr = div7(tc), tcc = tc - tr*7;
          float bv = jok ? bf2f(bias_s[((tr - jr + 6)*13 + (tcc - jc + 6))*6 + head]) : 0.f;
          s[i][nt][r] = jok ? (s[i][nt][r] + bv) : -3.0e38f;
        }
    }

    // softmax rows (each row: 4 nt x 16 lanes within quad), write P, keep 1/l
    float linv[2][4];
#pragma unroll
    for (int i = 0; i < 2; i++)
#pragma unroll
      for (int r = 0; r < 4; r++){
        float m = fmaxf(fmaxf(s[i][0][r], s[i][1][r]), fmaxf(s[i][2][r], s[i][3][r]));
#pragma unroll
        for (int off = 8; off > 0; off >>= 1) m = fmaxf(m, __shfl_xor(m, off));
        float l = 0.f;
        const int t = half*32 + i*16 + quad*4 + r;
#pragma unroll
        for (int nt = 0; nt < 4; nt++){
          float p = __expf(s[i][nt][r] - m);
          l += p;
          uXP[hl*4096 + t*64 + nt*16 + jj] = f2bf(p);
        }
#pragma unroll
        for (int off = 8; off > 0; off >>= 1) l += __shfl_xor(l, off);
        linv[i][r] = 1.f / l;
      }

    // PV: O = P(64x64 slice rows half*32..+32) x V(64x32)
    f32x4 o[2][2];
#pragma unroll
    for (int i = 0; i < 2; i++)
#pragma unroll
      for (int n2 = 0; n2 < 2; n2++) o[i][n2] = f4zero();
#pragma unroll
    for (int kt = 0; kt < 2; kt++){
      bf16x8 ap[2], bv[2];
#pragma unroll
      for (int i = 0; i < 2; i++)
        ap[i] = ldfrag(&uXP[hl*4096 + (half*32 + i*16 + l16)*64 + kt*32 + quad*8]);
#pragma unroll
      for (int n2 = 0; n2 < 2; n2++)
        bv[n2] = ldfrag(&vt[(hl*32 + n2*16 + l16)*64 + kt*32 + quad*8]);
#pragma unroll
      for (int i = 0; i < 2; i++)
#pragma unroll
        for (int n2 = 0; n2 < 2; n2++)
          o[i][n2] = mfma16(ap[i], bv[n2], o[i][n2]);
    }

    // store O rows < 49, spatial order (window reverse), bf16
#pragma unroll
    for (int i = 0; i < 2; i++)
#pragma unroll
      for (int r = 0; r < 4; r++){
        const int t = half*32 + i*16 + quad*4 + r;
        if (t < 49){
          const int tr = div7(t), tcc = t - tr*7;
          const size_t base =
            ((size_t)b*3136 + (size_t)((wr*7 + tr)*56 + wc*7 + tcc))*192 + head*32;
          const float inv = linv[i][r];
          attn[base + l16]      = f2bf(o[i][0][r] * inv);
          attn[base + 16 + l16] = f2bf(o[i][1][r] * inv);
        }
      }
  }
}

// ---------------- k2: proj GEMM (100352 x 192) @ (192 x 192)^T + bias ----------------
// grid (784, 3); block 256 (4 waves); tile M=128, N=64
#define ATS 200   // padded A-tile stride
__global__ __launch_bounds__(256, 3) void wa_k2(
    const unsigned short* __restrict__ a, const unsigned short* __restrict__ wp,
    const float* __restrict__ pb, float* __restrict__ out)
{
  __shared__ __align__(16) unsigned short at[128*ATS];
  const int mblk = blockIdx.x;
  const int nblk = blockIdx.y;
  const int tid  = threadIdx.x;
  const int wave = tid >> 6;
  const int lane = tid & 63;
  const int quad = lane >> 4;
  const int l16  = lane & 15;

  // stage A tile 128x192 (bf16) -> LDS padded
  {
    const unsigned short* src = a + (size_t)mblk*128*192;
    for (int i = tid; i < 128*24; i += 256){
      int r = i / 24, c = i - r*24;
      *(uint4*)&at[r*ATS + c*8] = *(const uint4*)&src[r*192 + c*8];
    }
  }
  __syncthreads();

  f32x4 acc[2][4];
#pragma unroll
  for (int i = 0; i < 2; i++)
#pragma unroll
    for (int nt = 0; nt < 4; nt++) acc[i][nt] = f4zero();

#pragma unroll
  for (int kt = 0; kt < 6; kt++){
    bf16x8 av[2], bw[4];
#pragma unroll
    for (int i = 0; i < 2; i++)
      av[i] = ldfrag(&at[((wave*2 + i)*16 + l16)*ATS + kt*32 + quad*8]);
#pragma unroll
    for (int nt = 0; nt < 4; nt++)
      bw[nt] = ldfrag(&wp[(size_t)(nblk*64 + nt*16 + l16)*192 + kt*32 + quad*8]);
#pragma unroll
    for (int i = 0; i < 2; i++)
#pragma unroll
      for (int nt = 0; nt < 4; nt++)
        acc[i][nt] = mfma16(av[i], bw[nt], acc[i][nt]);
  }

#pragma unroll
  for (int nt = 0; nt < 4; nt++){
    const int col = nblk*64 + nt*16 + l16;
    const float bias = pb[col];
#pragma unroll
    for (int i = 0; i < 2; i++)
#pragma unroll
      for (int r = 0; r < 4; r++){
        const int row = mblk*128 + (wave*2 + i)*16 + quad*4 + r;
        out[(size_t)row*192 + col] = acc[i][nt][r] + bias;
      }
  }
}

extern "C" void kernel_launch(void* const* d_in, const int* in_sizes, int n_in,
                              void* d_out, int out_size, void* d_ws, size_t ws_size,
                              hipStream_t stream) {
  (void)in_sizes; (void)n_in; (void)out_size; (void)ws_size;
  const float* x      = (const float*)d_in[0];
  const float* gamma  = (const float*)d_in[1];
  const float* rpb    = (const float*)d_in[2];
  const float* qkv_w  = (const float*)d_in[3];
  const float* qkv_b  = (const float*)d_in[4];
  const float* proj_w = (const float*)d_in[5];
  const float* proj_b = (const float*)d_in[6];

  unsigned short* wq   = (unsigned short*)d_ws;            // 576*192
  unsigned short* wp   = wq + 576*192;                     // 192*192
  unsigned short* attn = wq + 576*192 + 192*192;           // 100352*192 bf16
  float* out = (float*)d_out;

  hipLaunchKernelGGL(wa_prep, dim3(432), dim3(256), 0, stream, qkv_w, proj_w, wq, wp);
  hipLaunchKernelGGL(wa_k1, dim3(4096), dim3(384), 0, stream,
                     x, gamma, rpb, wq, qkv_b, attn);
  hipLaunchKernelGGL(wa_k2, dim3(784, 3), dim3(256), 0, stream,
                     attn, wp, proj_b, out);
}

// Round 4
// 430.360 us; speedup vs baseline: 3.3791x; 1.0595x over previous
//
#include <hip/hip_runtime.h>

// WindowAttention MFMA v2: B=32, 56x56, C=192, heads=6, d=32, ws=7, NW=49
//  prep: weights -> bf16; expand rpb+RPI+mask -> bt[6][64][64] fp32
//  k1:   per (window, 3-head half): LN -> MFMA QKV -> MFMA attention -> bf16 out (ws)
//        padded LDS strides (40/72) to kill bank conflicts; bias via global bt
//  k2:   proj GEMM (100352x192x192) direct-global MFMA (no LDS, no barrier)

typedef __bf16 bf16x8 __attribute__((ext_vector_type(8)));
typedef float  f32x4  __attribute__((ext_vector_type(4)));
union U128 { uint4 u; bf16x8 v; };

__device__ __forceinline__ f32x4 mfma16(bf16x8 a, bf16x8 b, f32x4 c){
  return __builtin_amdgcn_mfma_f32_16x16x32_bf16(a, b, c, 0, 0, 0);
}
__device__ __forceinline__ f32x4 f4zero(){
  f32x4 z; z[0]=0.f; z[1]=0.f; z[2]=0.f; z[3]=0.f; return z;
}
__device__ __forceinline__ unsigned short f2bf(float f){
  union{float f; unsigned int i;} x; x.f = f;
  unsigned int r = x.i + 0x7fffu + ((x.i >> 16) & 1u);  // RNE
  return (unsigned short)(r >> 16);
}
__device__ __forceinline__ bf16x8 ldfrag(const unsigned short* p){
  U128 x; x.u = *(const uint4*)p; return x.v;
}
__device__ __forceinline__ int div7(int t){ return (t * 9363) >> 16; }  // exact for t<64

// ---------------- prep: weights fp32 -> bf16, bias table expand ----------------
__global__ void wa_prep(const float* __restrict__ qkv_w, const float* __restrict__ proj_w,
                        const float* __restrict__ rpb,
                        unsigned short* __restrict__ wq, unsigned short* __restrict__ wp,
                        float* __restrict__ bt){
  int i = blockIdx.x * 256 + threadIdx.x;
  if (i < 576*192) wq[i] = f2bf(qkv_w[i]);
  if (i < 192*192) wp[i] = f2bf(proj_w[i]);
  if (i < 6*64*64){
    int head = i >> 12, t = (i >> 6) & 63, j = i & 63;
    float v;
    if (t < 49 && j < 49){
      int tr = div7(t), tc = t - tr*7;
      int jr = div7(j), jc = j - jr*7;
      v = rpb[((tr - jr + 6)*13 + (tc - jc + 6))*6 + head];
    } else {
      v = (j >= 49) ? -3.0e38f : 0.0f;   // mask folded into bias
    }
    bt[i] = v;
  }
}

// ---------------- k1: LN + QKV + attention (MFMA) ----------------
// grid 4096 = 2048 windows x 2 half (3 heads each); block 384 (6 waves)
// LDS strides: xn 216 (=3*72), qs/ks 40, vt 72, P 72  -> all <=2-way bank aliasing
#define XNS 216
__global__ __launch_bounds__(384, 2) void wa_k1(
    const float* __restrict__ x, const float* __restrict__ gamma,
    const float* __restrict__ bt, const unsigned short* __restrict__ wq,
    const float* __restrict__ qkv_b, unsigned short* __restrict__ attn)
{
  __shared__ __align__(16) unsigned short uXP[3*64*72];  // xn (stride 216) then P[3][64][72]
  __shared__ __align__(16) unsigned short qs[3*64*40];   // Q (scaled) [hl][t][d], stride 40
  __shared__ __align__(16) unsigned short ks[3*64*40];   // K [hl][t][d], stride 40
  __shared__ __align__(16) unsigned short vt[3*32*72];   // V^T [hl][d][t], stride 72

  const int blk  = blockIdx.x;
  const int wi   = blk >> 1;
  const int h0   = (blk & 1) * 3;
  const int b    = wi >> 6;
  const int wr   = (wi >> 3) & 7;
  const int wc   = wi & 7;
  const int tid  = threadIdx.x;
  const int wave = tid >> 6;
  const int lane = tid & 63;
  const int quad = lane >> 4;
  const int l16  = lane & 15;

  // ---- LayerNorm -> uXP (bf16, stride XNS), zero pad rows 49..63 ----
  {
    const float g0 = gamma[lane], g1 = gamma[lane+64], g2 = gamma[lane+128];
    const float* xb = x + (size_t)b * 3136 * 192;
    for (int t = wave; t < 49; t += 6){
      int r = div7(t), c = t - r*7;
      const float* xt = xb + (size_t)((wr*7 + r)*56 + (wc*7 + c)) * 192;
      float v0 = xt[lane], v1 = xt[lane+64], v2 = xt[lane+128];
      float s  = v0 + v1 + v2;
      float sq = v0*v0 + v1*v1 + v2*v2;
#pragma unroll
      for (int off = 32; off > 0; off >>= 1){
        s  += __shfl_xor(s,  off);
        sq += __shfl_xor(sq, off);
      }
      float mu  = s * (1.0f/192.0f);
      float var = sq * (1.0f/192.0f) - mu*mu;
      float inv = rsqrtf(var + 1e-5f);
      uXP[t*XNS + lane      ] = f2bf((v0 - mu)*inv*g0);
      uXP[t*XNS + lane + 64 ] = f2bf((v1 - mu)*inv*g1);
      uXP[t*XNS + lane + 128] = f2bf((v2 - mu)*inv*g2);
    }
    // zero rows 49..63 (cols 0..191)
    const uint4 z = {0u,0u,0u,0u};
    for (int i = tid; i < 15*24; i += 384){
      int r = 49 + i/24, c8 = i - (i/24)*24;
      *(uint4*)&uXP[r*XNS + c8*8] = z;
    }
  }
  __syncthreads();

  // ---- QKV GEMM: wave w: section sec=w>>1 (q/k/v), 48 cols ----
  {
    const int sec = wave >> 1;
    const int n0  = sec*192 + h0*32 + (wave & 1)*48;
    f32x4 acc[4][3];
#pragma unroll
    for (int mt = 0; mt < 4; mt++)
#pragma unroll
      for (int nt = 0; nt < 3; nt++) acc[mt][nt] = f4zero();

#pragma unroll
    for (int kt = 0; kt < 6; kt++){
      bf16x8 a[4], bw[3];
#pragma unroll
      for (int mt = 0; mt < 4; mt++)
        a[mt] = ldfrag(&uXP[(mt*16 + l16)*XNS + kt*32 + quad*8]);
#pragma unroll
      for (int nt = 0; nt < 3; nt++)
        bw[nt] = ldfrag(&wq[(size_t)(n0 + nt*16 + l16)*192 + kt*32 + quad*8]);
#pragma unroll
      for (int mt = 0; mt < 4; mt++)
#pragma unroll
        for (int nt = 0; nt < 3; nt++)
          acc[mt][nt] = mfma16(a[mt], bw[nt], acc[mt][nt]);
    }
    const float scale = 0.17677669529663687f;  // 1/sqrt(32)
#pragma unroll
    for (int nt = 0; nt < 3; nt++){
      const int bc = (wave & 1)*48 + nt*16 + l16;  // 0..95 within section
      const int hl = bc >> 5, d = bc & 31;
      const float bias = qkv_b[n0 + nt*16 + l16];
#pragma unroll
      for (int mt = 0; mt < 4; mt++)
#pragma unroll
        for (int r = 0; r < 4; r++){
          const int row = mt*16 + quad*4 + r;
          const float val = acc[mt][nt][r] + bias;
          if (sec == 0)      qs[(hl*64 + row)*40 + d] = f2bf(val * scale);
          else if (sec == 1) ks[(hl*64 + row)*40 + d] = f2bf(val);
          else               vt[(hl*32 + d)*72 + row] = f2bf(val);
        }
    }
  }
  __syncthreads();

  // ---- Attention: wave -> (local head hl = w>>1, row-half = w&1) ----
  {
    const int hl   = wave >> 1;
    const int half = wave & 1;
    const int head = h0 + hl;

    bf16x8 aq[2];
#pragma unroll
    for (int i = 0; i < 2; i++)
      aq[i] = ldfrag(&qs[(hl*64 + half*32 + i*16 + l16)*40 + quad*8]);

    f32x4 s[2][4];
#pragma unroll
    for (int nt = 0; nt < 4; nt++){
      bf16x8 bk = ldfrag(&ks[(hl*64 + nt*16 + l16)*40 + quad*8]);
#pragma unroll
      for (int i = 0; i < 2; i++)
        s[i][nt] = mfma16(aq[i], bk, f4zero());
    }

    // bias+mask via precomputed table (coalesced L2 loads)
    {
      const float* bth = bt + head*4096;
#pragma unroll
      for (int i = 0; i < 2; i++)
#pragma unroll
        for (int r = 0; r < 4; r++){
          const int t = half*32 + i*16 + quad*4 + r;
          const float* row = bth + t*64 + l16;
#pragma unroll
          for (int nt = 0; nt < 4; nt++)
            s[i][nt][r] += row[nt*16];
        }
    }

    // softmax rows; write P (stride 72); keep 1/l
    float linv[2][4];
#pragma unroll
    for (int i = 0; i < 2; i++)
#pragma unroll
      for (int r = 0; r < 4; r++){
        float m = fmaxf(fmaxf(s[i][0][r], s[i][1][r]), fmaxf(s[i][2][r], s[i][3][r]));
#pragma unroll
        for (int off = 8; off > 0; off >>= 1) m = fmaxf(m, __shfl_xor(m, off));
        float l = 0.f;
        const int t = half*32 + i*16 + quad*4 + r;
#pragma unroll
        for (int nt = 0; nt < 4; nt++){
          float p = __expf(s[i][nt][r] - m);
          l += p;
          uXP[hl*4608 + t*72 + nt*16 + l16] = f2bf(p);
        }
#pragma unroll
        for (int off = 8; off > 0; off >>= 1) l += __shfl_xor(l, off);
        linv[i][r] = 1.f / l;
      }

    // PV: O(32x32 slice) = P rows[half*32..+32) x V(64x32)
    f32x4 o[2][2];
#pragma unroll
    for (int i = 0; i < 2; i++)
#pragma unroll
      for (int n2 = 0; n2 < 2; n2++) o[i][n2] = f4zero();
#pragma unroll
    for (int kt = 0; kt < 2; kt++){
      bf16x8 ap[2], bv[2];
#pragma unroll
      for (int i = 0; i < 2; i++)
        ap[i] = ldfrag(&uXP[hl*4608 + (half*32 + i*16 + l16)*72 + kt*32 + quad*8]);
#pragma unroll
      for (int n2 = 0; n2 < 2; n2++)
        bv[n2] = ldfrag(&vt[(hl*32 + n2*16 + l16)*72 + kt*32 + quad*8]);
#pragma unroll
      for (int i = 0; i < 2; i++)
#pragma unroll
        for (int n2 = 0; n2 < 2; n2++)
          o[i][n2] = mfma16(ap[i], bv[n2], o[i][n2]);
    }

    // store O rows < 49, spatial order (window reverse), bf16
#pragma unroll
    for (int i = 0; i < 2; i++)
#pragma unroll
      for (int r = 0; r < 4; r++){
        const int t = half*32 + i*16 + quad*4 + r;
        if (t < 49){
          const int tr = div7(t), tcc = t - tr*7;
          const size_t base =
            ((size_t)b*3136 + (size_t)((wr*7 + tr)*56 + wc*7 + tcc))*192 + head*32;
          const float inv = linv[i][r];
          attn[base + l16]      = f2bf(o[i][0][r] * inv);
          attn[base + 16 + l16] = f2bf(o[i][1][r] * inv);
        }
      }
  }
}

// ---------------- k2: proj GEMM direct-global (no LDS, no barrier) ----------------
// grid (784, 3); block 256 (4 waves); per block M=128, N=64; K=192 fully unrolled
__global__ __launch_bounds__(256, 4) void wa_k2(
    const unsigned short* __restrict__ a, const unsigned short* __restrict__ wp,
    const float* __restrict__ pb, float* __restrict__ out)
{
  const int mblk = blockIdx.x;
  const int nblk = blockIdx.y;
  const int tid  = threadIdx.x;
  const int wave = tid >> 6;
  const int lane = tid & 63;
  const int quad = lane >> 4;
  const int l16  = lane & 15;

  f32x4 acc[2][4];
#pragma unroll
  for (int i = 0; i < 2; i++)
#pragma unroll
    for (int nt = 0; nt < 4; nt++) acc[i][nt] = f4zero();

#pragma unroll
  for (int kt = 0; kt < 6; kt++){
    bf16x8 av[2], bw[4];
#pragma unroll
    for (int i = 0; i < 2; i++)
      av[i] = ldfrag(&a[(size_t)(mblk*128 + (wave*2 + i)*16 + l16)*192 + kt*32 + quad*8]);
#pragma unroll
    for (int nt = 0; nt < 4; nt++)
      bw[nt] = ldfrag(&wp[(size_t)(nblk*64 + nt*16 + l16)*192 + kt*32 + quad*8]);
#pragma unroll
    for (int i = 0; i < 2; i++)
#pragma unroll
      for (int nt = 0; nt < 4; nt++)
        acc[i][nt] = mfma16(av[i], bw[nt], acc[i][nt]);
  }

#pragma unroll
  for (int nt = 0; nt < 4; nt++){
    const int col = nblk*64 + nt*16 + l16;
    const float bias = pb[col];
#pragma unroll
    for (int i = 0; i < 2; i++)
#pragma unroll
      for (int r = 0; r < 4; r++){
        const int row = mblk*128 + (wave*2 + i)*16 + quad*4 + r;
        out[(size_t)row*192 + col] = acc[i][nt][r] + bias;
      }
  }
}

extern "C" void kernel_launch(void* const* d_in, const int* in_sizes, int n_in,
                              void* d_out, int out_size, void* d_ws, size_t ws_size,
                              hipStream_t stream) {
  (void)in_sizes; (void)n_in; (void)out_size; (void)ws_size;
  const float* x      = (const float*)d_in[0];
  const float* gamma  = (const float*)d_in[1];
  const float* rpb    = (const float*)d_in[2];
  const float* qkv_w  = (const float*)d_in[3];
  const float* qkv_b  = (const float*)d_in[4];
  const float* proj_w = (const float*)d_in[5];
  const float* proj_b = (const float*)d_in[6];

  unsigned short* wq   = (unsigned short*)d_ws;            // 576*192 bf16
  unsigned short* wp   = wq + 576*192;                     // 192*192 bf16
  float* bt            = (float*)(wp + 192*192);           // 6*64*64 fp32
  unsigned short* attn = (unsigned short*)(bt + 6*64*64);  // 100352*192 bf16
  float* out = (float*)d_out;

  hipLaunchKernelGGL(wa_prep, dim3(432), dim3(256), 0, stream,
                     qkv_w, proj_w, rpb, wq, wp, bt);
  hipLaunchKernelGGL(wa_k1, dim3(4096), dim3(384), 0, stream,
                     x, gamma, bt, wq, qkv_b, attn);
  hipLaunchKernelGGL(wa_k2, dim3(784, 3), dim3(256), 0, stream,
                     attn, wp, proj_b, out);
}